// Round 8
// baseline (129.357 us; speedup 1.0000x reference)
//
#include <hip/hip_runtime.h>
#include <stdint.h>

// Problem: LTCCell  B=256, I=512, H=512. ALL tensors float32, output float32.
// R5: 2x TLP -> no change. R6: prefetch+swizzle -> worse. R7: zero-trans
// polynomial -> NO CHANGE (47us, VALUBusy 56%). Conclusion: limiter is
// memory-side, occupancy- and content-independent: the inner loop walks
// FOUR 1MB param streams with identical index patterns -> L2 set-aliasing,
// correlated L3-latency misses. R8: pack pre-pass -> ONE float4 stream
// (a, c=mu*a, W, We=W*er): 1x global_load_dwordx4 per row instead of 4x
// dword, no aliasing, -2 VALU muls/row; clamp via v_med3.
constexpr int NB = 256;
constexpr int NI = 512;
constexpr int NH = 512;

constexpr int TB    = 8;    // batches register-blocked per lane
constexpr int NT    = 32;   // batch tiles: 256/8
constexpr int CHUNK = 32;   // reduction rows per block
constexpr int NSPL  = 32;   // splits: 16 sensory chunks + 16 inter chunks
constexpr int HBLK  = 256;  // h columns per block (== blockDim.x)
constexpr int SIDE_ELEMS = 512 * 512;   // per-side param elements

// Odd poly for sigmoid(z)-0.5 = z*P(z^2), |z|<=7, max err ~3.5e-3.
__device__ __constant__ const float SC0 =  0.24781886f;
__device__ __constant__ const float SC1 = -0.01739900f;
__device__ __constant__ const float SC2 =  9.68558e-4f;
__device__ __constant__ const float SC3 = -3.09967e-5f;
__device__ __constant__ const float SC4 =  5.03772e-7f;
__device__ __constant__ const float SC5 = -3.21180e-9f;

__device__ __forceinline__ float clamp7(float z) {
#if __has_builtin(__builtin_amdgcn_fmed3f)
    return __builtin_amdgcn_fmed3f(z, -7.0f, 7.0f);   // v_med3_f32
#else
    return fminf(fmaxf(z, -7.0f), 7.0f);
#endif
}

// Pack pre-pass: 4 param streams -> one float4 stream (a, c, W, We).
// side 0 = sensory, side 1 = inter. 2048 blocks x 256 thr, ~17MB traffic.
__global__ __launch_bounds__(256) void ltc_pack(
    const float* __restrict__ smu, const float* __restrict__ ssg,
    const float* __restrict__ sW,  const float* __restrict__ ser,
    const float* __restrict__ imu, const float* __restrict__ isg,
    const float* __restrict__ iW,  const float* __restrict__ ier,
    float4* __restrict__ ppk)
{
    const int side = blockIdx.x >> 10;               // 1024 blocks per side
    const int e    = (blockIdx.x & 1023) * 256 + threadIdx.x;  // < SIDE_ELEMS
    const float* mu = side ? imu : smu;
    const float* sg = side ? isg : ssg;
    const float* W  = side ? iW  : sW;
    const float* er = side ? ier : ser;
    const float a  = sg[e];
    const float w  = W[e];
    float4 p;
    p.x = a;
    p.y = mu[e] * a;
    p.z = w;
    p.w = w * er[e];
    ppk[side * SIDE_ELEMS + e] = p;
}

// Each block = (split sigma, batch tile, h half). 2048 blocks x 256 thr.
// Lane <-> h column, 8 batches register-blocked per lane. Partials combined
// via f32 atomics into the f32 workspace.
__global__ __launch_bounds__(256, 6) void ltc_accum(
    const float* __restrict__ inputs,   // NB x NI
    const float* __restrict__ state,    // NB x NH
    const float4* __restrict__ ppk,     // packed (a, c, W, We)
    float* __restrict__ wsNum, float* __restrict__ wsDen)
{
    __shared__ float xs[CHUNK][TB];   // x/state chunk, [row][batch]

    const int bi    = blockIdx.x;
    const int sigma = bi & (NSPL - 1);          // 32 splits
    const int btile = (bi >> 5) & (NT - 1);     // 32 batch tiles
    const int hhalf = bi >> 10;                 // 2 h halves
    const int b0 = btile * TB;
    const int h  = hhalf * HBLK + threadIdx.x;

    const bool sens = sigma < 16;
    const int  r0   = (sens ? sigma : sigma - 16) * CHUNK;

    const float*  __restrict__ src = sens ? inputs : state;       // NB x 512
    const float4* __restrict__ Pp  = ppk + (sens ? 0 : SIDE_ELEMS);

    // Stage x/state chunk to LDS, [row][batch] layout. CHUNK*TB == 256.
    {
        const int ii = threadIdx.x >> 3, bb = threadIdx.x & (TB - 1);
        xs[ii][bb] = src[(b0 + bb) * 512 + r0 + ii];
    }
    __syncthreads();

    float numA[TB], denA[TB];                 // sums of We*g and W*g
#pragma unroll
    for (int bb = 0; bb < TB; ++bb) { numA[bb] = 0.f; denA[bb] = 0.f; }
    float sWsum = 0.f, sWesum = 0.f;          // sums of W and We

    // sigma(z) ~= 0.5 + zc*P5(zc^2), zc = med3(z,-7,7), z = x*a - c
#pragma unroll 2
    for (int ii = 0; ii < CHUNK; ++ii) {
        const float4 P = Pp[(r0 + ii) * NH + h];   // one dwordx4, coalesced
        const float a = P.x, c = P.y, W = P.z, We = P.w;
        sWsum  += W;
        sWesum += We;
#pragma unroll
        for (int bb = 0; bb < TB; ++bb) {
            const float z  = __builtin_fmaf(xs[ii][bb], a, -c);
            const float zc = clamp7(z);
            const float s  = zc * zc;
            float pl = __builtin_fmaf(SC5, s, SC4);
            pl = __builtin_fmaf(pl, s, SC3);
            pl = __builtin_fmaf(pl, s, SC2);
            pl = __builtin_fmaf(pl, s, SC1);
            pl = __builtin_fmaf(pl, s, SC0);
            const float g = zc * pl;               // sigma - 0.5
            denA[bb] = __builtin_fmaf(W,  g, denA[bb]);
            numA[bb] = __builtin_fmaf(We, g, numA[bb]);
        }
    }

#pragma unroll
    for (int bb = 0; bb < TB; ++bb) {
        const float den = __builtin_fmaf(0.5f, sWsum,  denA[bb]);
        const float num = __builtin_fmaf(0.5f, sWesum, numA[bb]);
        unsafeAtomicAdd(&wsNum[(b0 + bb) * NH + h], num);
        unsafeAtomicAdd(&wsDen[(b0 + bb) * NH + h], den);
    }
}

// Epilogue: one thread per (b,h). Exact math (off the hot path).
__global__ __launch_bounds__(256) void ltc_epilogue(
    const float* __restrict__ state,
    const float* __restrict__ vleak, const float* __restrict__ gleak,
    const float* __restrict__ cm,
    const float* __restrict__ wsNum, const float* __restrict__ wsDen,
    float* __restrict__ out)
{
    const int t = blockIdx.x * 256 + threadIdx.x;  // < NB*NH
    const int h = t & (NH - 1);
    const float st = state[t];
    const float gl = gleak[h];
    const float vl = vleak[h];
    const float c  = cm[h];
    const float wnum = wsNum[t];
    const float wden = wsDen[t];
    const float eps = 1e-8f;
    const float G = gl + wden;
    const float tau = c / (G + eps);
    const float numerator = c * st + gl * vl + wnum;
    const float denominator = c + G;
    const float v_inf = numerator / (denominator + eps);
    const float next = v_inf + (st - v_inf) * expf(-0.1f / (tau + eps));
    out[t] = tanhf(next);
}

extern "C" void kernel_launch(void* const* d_in, const int* in_sizes, int n_in,
                              void* d_out, int out_size, void* d_ws, size_t ws_size,
                              hipStream_t stream) {
    const float* inputs = (const float*)d_in[0];
    const float* state  = (const float*)d_in[1];
    const float* smu    = (const float*)d_in[2];
    const float* ssg    = (const float*)d_in[3];
    const float* sW     = (const float*)d_in[4];
    const float* ser    = (const float*)d_in[5];
    const float* imu    = (const float*)d_in[6];
    const float* isg    = (const float*)d_in[7];
    const float* iW     = (const float*)d_in[8];
    const float* ier    = (const float*)d_in[9];
    const float* vleak  = (const float*)d_in[10];
    const float* gleak  = (const float*)d_in[11];
    const float* cm     = (const float*)d_in[12];

    // ws layout: [packed params 8.4MB][wsNum 512KB][wsDen 512KB]
    float4* ppk   = (float4*)d_ws;
    float*  wsNum = (float*)((char*)d_ws + 2ull * SIDE_ELEMS * sizeof(float4));
    float*  wsDen = wsNum + NB * NH;

    // ws is re-poisoned (0xAA) before every timed launch -> zero accumulators.
    hipMemsetAsync((void*)wsNum, 0, 2ull * NB * NH * sizeof(float), stream);

    ltc_pack<<<dim3(2048), dim3(256), 0, stream>>>(
        smu, ssg, sW, ser, imu, isg, iW, ier, ppk);
    ltc_accum<<<dim3(NSPL * NT * 2), dim3(256), 0, stream>>>(
        inputs, state, ppk, wsNum, wsDen);
    ltc_epilogue<<<dim3(NB * NH / 256), dim3(256), 0, stream>>>(
        state, vleak, gleak, cm, wsNum, wsDen, (float*)d_out);
}

// Round 9
// 127.201 us; speedup vs baseline: 1.0169x; 1.0169x over previous
//
#include <hip/hip_runtime.h>
#include <stdint.h>

// Problem: LTCCell  B=256, I=512, H=512. ALL tensors float32, output float32.
// R5-R8 established: limiter is occupancy/content-independent, ~18us idle.
// Last suspect: 8.4M device-scope f32 atomics (WRITE_SIZE == 4B x atomics in
// every round -> each RMW resolves at the memory-side fabric; ~27us serial).
// R9: ATOMIC-ECTOMY. Each split-block stores partial (num,den) as plain
// coalesced float2 into its private slice part[s][t]; fused reduce+epilogue
// kernel sums S slices and finishes. No atomics -> no ws memset. Pack kernel
// dropped (R8: -4.7us accum but +10us dispatch). 2 dispatches total.
constexpr int NB = 256;
constexpr int NH = 512;
constexpr int NTGT = NB * NH;          // 131072 output targets

constexpr int TB    = 8;    // batches register-blocked per lane
constexpr int CHUNK = 32;   // rows per LDS-staged chunk
constexpr int HBLK  = 256;  // h columns per block (== blockDim.x)

// Odd poly for sigmoid(z)-0.5 = z*P5(z^2), |z|<=7, max err ~3.5e-3.
__device__ __constant__ const float SC0 =  0.24781886f;
__device__ __constant__ const float SC1 = -0.01739900f;
__device__ __constant__ const float SC2 =  9.68558e-4f;
__device__ __constant__ const float SC3 = -3.09967e-5f;
__device__ __constant__ const float SC4 =  5.03772e-7f;
__device__ __constant__ const float SC5 = -3.21180e-9f;

__device__ __forceinline__ float clamp7(float z) {
#if __has_builtin(__builtin_amdgcn_fmed3f)
    return __builtin_amdgcn_fmed3f(z, -7.0f, 7.0f);   // v_med3_f32
#else
    return fminf(fmaxf(z, -7.0f), 7.0f);
#endif
}

// Block = (split s, btile, hhalf). Each block reduces CPB*32 rows of the
// 1024-row (sensory||inter) axis for 2048 targets, then stores one float2
// partial per target into part[s*NTGT + t]. Plain stores, no atomics.
__global__ __launch_bounds__(256, 8) void ltc_accum(
    const float* __restrict__ inputs,   // NB x 512
    const float* __restrict__ state,    // NB x 512
    const float* __restrict__ smu, const float* __restrict__ ssg,
    const float* __restrict__ sW,  const float* __restrict__ ser,
    const float* __restrict__ imu, const float* __restrict__ isg,
    const float* __restrict__ iW,  const float* __restrict__ ier,
    float2* __restrict__ part,
    int sBits, int CPB)
{
    __shared__ float xs[CHUNK][TB];   // x/state chunk, [row][batch]

    const int bi    = blockIdx.x;
    const int S     = 1 << sBits;
    const int s     = bi & (S - 1);
    const int rest  = bi >> sBits;
    const int btile = rest & 31;                // 32 batch tiles (256/TB)
    const int hhalf = rest >> 5;                // 2 h halves
    const int b0 = btile * TB;
    const int h  = hhalf * HBLK + threadIdx.x;
    const int g0 = s * (CPB * CHUNK);           // first global row

    float numA[TB], denA[TB];                   // sums of We*g and W*g
#pragma unroll
    for (int bb = 0; bb < TB; ++bb) { numA[bb] = 0.f; denA[bb] = 0.f; }
    float sWsum = 0.f, sWesum = 0.f;            // sums of W and We

    for (int c = 0; c < CPB; ++c) {
        const int g    = g0 + c * CHUNK;        // global row, 0..1023
        const bool sens = g < 512;
        const int  r0   = g & 511;

        const float* __restrict__ src = sens ? inputs : state;
        const float* __restrict__ Pmu = sens ? smu : imu;
        const float* __restrict__ Psg = sens ? ssg : isg;
        const float* __restrict__ PW  = sens ? sW  : iW;
        const float* __restrict__ Per = sens ? ser : ier;

        // Stage chunk to LDS, coalesced global read (ii contiguous).
        if (c) __syncthreads();                 // xs reuse guard
        {
            const int bb = threadIdx.x >> 5, ii = threadIdx.x & 31;
            const float v = src[(b0 + bb) * 512 + r0 + ii];
            xs[ii][bb] = v;
        }
        __syncthreads();

        // sigma(z) ~= 0.5 + zc*P5(zc^2), zc = med3(z,-7,7), z = x*a - c
#pragma unroll 2
        for (int ii = 0; ii < CHUNK; ++ii) {
            const int p = (r0 + ii) * NH + h;   // coalesced across lanes
            const float a  = Psg[p];
            const float cc = Pmu[p] * a;
            const float W  = PW[p];
            const float We = W * Per[p];
            sWsum  += W;
            sWesum += We;
#pragma unroll
            for (int bb = 0; bb < TB; ++bb) {
                const float z  = __builtin_fmaf(xs[ii][bb], a, -cc);
                const float zc = clamp7(z);
                const float sq = zc * zc;
                float pl = __builtin_fmaf(SC5, sq, SC4);
                pl = __builtin_fmaf(pl, sq, SC3);
                pl = __builtin_fmaf(pl, sq, SC2);
                pl = __builtin_fmaf(pl, sq, SC1);
                pl = __builtin_fmaf(pl, sq, SC0);
                const float gg = zc * pl;       // sigma - 0.5
                denA[bb] = __builtin_fmaf(W,  gg, denA[bb]);
                numA[bb] = __builtin_fmaf(We, gg, numA[bb]);
            }
        }
    }

    // Plain coalesced float2 stores: private slice, zero contention.
    float2* __restrict__ slice = part + (size_t)s * NTGT;
#pragma unroll
    for (int bb = 0; bb < TB; ++bb) {
        const float den = __builtin_fmaf(0.5f, sWsum,  denA[bb]);
        const float num = __builtin_fmaf(0.5f, sWesum, numA[bb]);
        slice[(b0 + bb) * NH + h] = make_float2(num, den);
    }
}

// Fused reduce + epilogue: thread t sums S partial slices, finishes exactly.
__global__ __launch_bounds__(256) void ltc_reduce_epilogue(
    const float* __restrict__ state,
    const float* __restrict__ vleak, const float* __restrict__ gleak,
    const float* __restrict__ cm,
    const float2* __restrict__ part, int S,
    float* __restrict__ out)
{
    const int t = blockIdx.x * 256 + threadIdx.x;  // < NTGT
    const int h = t & (NH - 1);

    float wnum = 0.f, wden = 0.f;
    for (int s = 0; s < S; ++s) {
        const float2 p = part[(size_t)s * NTGT + t];   // coalesced
        wnum += p.x; wden += p.y;
    }

    const float st = state[t];
    const float gl = gleak[h];
    const float vl = vleak[h];
    const float c  = cm[h];
    const float eps = 1e-8f;
    const float G = gl + wden;
    const float tau = c / (G + eps);
    const float numerator = c * st + gl * vl + wnum;
    const float denominator = c + G;
    const float v_inf = numerator / (denominator + eps);
    const float next = v_inf + (st - v_inf) * expf(-0.1f / (tau + eps));
    out[t] = tanhf(next);
}

extern "C" void kernel_launch(void* const* d_in, const int* in_sizes, int n_in,
                              void* d_out, int out_size, void* d_ws, size_t ws_size,
                              hipStream_t stream) {
    const float* inputs = (const float*)d_in[0];
    const float* state  = (const float*)d_in[1];
    const float* smu    = (const float*)d_in[2];
    const float* ssg    = (const float*)d_in[3];
    const float* sW     = (const float*)d_in[4];
    const float* ser    = (const float*)d_in[5];
    const float* imu    = (const float*)d_in[6];
    const float* isg    = (const float*)d_in[7];
    const float* iW     = (const float*)d_in[8];
    const float* ier    = (const float*)d_in[9];
    const float* vleak  = (const float*)d_in[10];
    const float* gleak  = (const float*)d_in[11];
    const float* cm     = (const float*)d_in[12];

    // Runtime split count: largest S in {32,16,8} whose partial buffer fits.
    // (R8 proved ws_size >= 9.4MB, so S=8 always fits.)
    int sBits;
    if      (ws_size >= 32ull * NTGT * sizeof(float2)) sBits = 5;
    else if (ws_size >= 16ull * NTGT * sizeof(float2)) sBits = 4;
    else                                               sBits = 3;
    const int S   = 1 << sBits;
    const int CPB = 32 / S;                 // 32-row chunks per block

    float2* part = (float2*)d_ws;

    ltc_accum<<<dim3(S * 64), dim3(256), 0, stream>>>(
        inputs, state, smu, ssg, sW, ser, imu, isg, iW, ier, part, sBits, CPB);
    ltc_reduce_epilogue<<<dim3(NTGT / 256), dim3(256), 0, stream>>>(
        state, vleak, gleak, cm, part, S, (float*)d_out);
}